// Round 14
// baseline (401.761 us; speedup 1.0000x reference)
//
#include <hip/hip_runtime.h>
#include <math.h>

typedef _Float16 f16;
typedef _Float16 f16x2 __attribute__((ext_vector_type(2)));
typedef _Float16 f16x8 __attribute__((ext_vector_type(8)));
typedef __fp16 fp16x2 __attribute__((ext_vector_type(2)));
typedef float f32x4 __attribute__((ext_vector_type(4)));

union F2U { f16x2 h; fp16x2 p; unsigned u; };
union U2H { uint2 q; f16x2 h[2]; f16 f[4]; };
union U4H { uint4 q; f16x2 h[4]; f16 f[8]; };

__device__ __forceinline__ f16x2 uAsH(unsigned u) { F2U c; c.u = u; return c.h; }
__device__ __forceinline__ unsigned hAsU(f16x2 h) { F2U c; c.h = h; return c.u; }
__device__ __forceinline__ unsigned pAsU(fp16x2 p) { F2U c; c.p = p; return c.u; }

constexpr size_t PL = (size_t)512 * 512 * 96;

// ---------------------------------------------------------------------------
// K12 v5 (unchanged from round 13): fused pointwise GEMM + depthwise conv.
// grid (512 batch, 3 conv), block 1024 (16 waves).
// ---------------------------------------------------------------------------
__global__ __launch_bounds__(1024, 4) void k12_fused(
    const float* __restrict__ x,
    const float* __restrict__ wq1, const float* __restrict__ bq1,
    const float* __restrict__ wk1, const float* __restrict__ bk1,
    const float* __restrict__ wv1, const float* __restrict__ bv1,
    const float* __restrict__ wqd, const float* __restrict__ bqd,
    const float* __restrict__ wkd, const float* __restrict__ bkd,
    const float* __restrict__ wvd, const float* __restrict__ bvd,
    f16* __restrict__ qo, f16* __restrict__ ko, f16* __restrict__ vo)
{
    __shared__ __align__(16) char sm[137600];
    f16* Xsh = (f16*)sm;                       // [512][104] f16; overlaid post-GEMM
    f16* Wsh = (f16*)(sm + 106496);            // [96][104] f16 pointwise w
    unsigned* wdx = (unsigned*)(sm + 126464);  // q/k: [27][48] u32; v: [96][27] u32
    float* bl1 = (float*)(sm + 136832);        // [96] pointwise bias
    float* bld = (float*)(sm + 137216);        // [96] depthwise bias

    const int tid = threadIdx.x;
    const int b = blockIdx.x;
    const int which = blockIdx.y;
    const int wv_ = tid >> 6, lane = tid & 63, lr = lane & 15, lk = lane >> 4;

    const float* w1 = (which == 0) ? wq1 : ((which == 1) ? wk1 : wv1);
    const float* b1 = (which == 0) ? bq1 : ((which == 1) ? bk1 : bv1);
    const float* wd = (which == 0) ? wqd : ((which == 1) ? wkd : wvd);
    const float* bd = (which == 0) ? bqd : ((which == 1) ? bkd : bvd);

    // ---- stage x (f32->f16), pointwise w, depthwise w, biases ----
    const float* xb = x + (size_t)b * 512 * 96;
    #pragma unroll
    for (int it = 0; it < 12; ++it) {
        int i = (tid + it * 1024) * 4;
        float4 v4 = *(const float4*)(xb + i);
        int r = i / 96, c = i % 96;
        f16x2 h01 = { (f16)v4.x, (f16)v4.y };
        f16x2 h23 = { (f16)v4.z, (f16)v4.w };
        uint2 st; st.x = hAsU(h01); st.y = hAsU(h23);
        *(uint2*)(Xsh + r * 104 + c) = st;
    }
    #pragma unroll
    for (int it = 0; it < 3; ++it) {
        int i = (tid + it * 1024) * 4;
        if (i < 9216) {
            float4 v4 = *(const float4*)(w1 + i);
            int co = i / 96, ci = i % 96;
            f16x2 h01 = { (f16)v4.x, (f16)v4.y };
            f16x2 h23 = { (f16)v4.z, (f16)v4.w };
            uint2 st; st.x = hAsU(h01); st.y = hAsU(h23);
            *(uint2*)(Wsh + co * 104 + ci) = st;
        }
    }
    if (which < 2) {
        for (int ii = tid; ii < 2592; ii += 1024) {
            int c = ii / 27, t2 = ii % 27;
            ((f16*)wdx)[t2 * 96 + c] = (f16)wd[ii];
        }
    } else {
        for (int ii = tid; ii < 2592; ii += 1024) {
            int c = ii / 27, t2 = ii % 27;
            f16 hh = (f16)wd[ii];
            f16x2 hp = { hh, hh };
            wdx[c * 27 + t2] = hAsU(hp);
        }
    }
    if (tid < 96) { bl1[tid] = b1[tid]; bld[tid] = bd[tid]; }
    __syncthreads();

    // ---- pointwise GEMM: wave = 32 positions x 96 out-channels ----
    f32x4 acc[2][6];
    #pragma unroll
    for (int pg = 0; pg < 2; ++pg)
        #pragma unroll
        for (int cg = 0; cg < 6; ++cg) acc[pg][cg] = f32x4{0.f, 0.f, 0.f, 0.f};

    if (which < 2) {
        #pragma unroll
        for (int ks = 0; ks < 3; ++ks) {
            f16x8 bfr[6];
            #pragma unroll
            for (int cg = 0; cg < 6; ++cg)
                bfr[cg] = *(const f16x8*)(Wsh + (cg * 16 + lr) * 104 + ks * 32 + lk * 8);
            #pragma unroll
            for (int pg = 0; pg < 2; ++pg) {
                f16x8 a = *(const f16x8*)(Xsh + (wv_ * 32 + pg * 16 + lr) * 104 + ks * 32 + lk * 8);
                #pragma unroll
                for (int cg = 0; cg < 6; ++cg)
                    acc[pg][cg] = __builtin_amdgcn_mfma_f32_16x16x32_f16(bfr[cg], a, acc[pg][cg], 0, 0, 0);
            }
        }
    } else {
        #pragma unroll
        for (int ks = 0; ks < 3; ++ks) {
            f16x8 bfr[6];
            #pragma unroll
            for (int cg = 0; cg < 6; ++cg)
                bfr[cg] = *(const f16x8*)(Wsh + (cg * 16 + lr) * 104 + ks * 32 + lk * 8);
            #pragma unroll
            for (int pg = 0; pg < 2; ++pg) {
                f16x8 a = *(const f16x8*)(Xsh + (wv_ * 32 + pg * 16 + lr) * 104 + ks * 32 + lk * 8);
                #pragma unroll
                for (int cg = 0; cg < 6; ++cg)
                    acc[pg][cg] = __builtin_amdgcn_mfma_f32_16x16x32_f16(a, bfr[cg], acc[pg][cg], 0, 0, 0);
            }
        }
    }
    __syncthreads();   // all Xsh reads done before overlay

    // ---- write GEMM out (+bias) over the slab ----
    if (which < 2) {
        #pragma unroll
        for (int pg = 0; pg < 2; ++pg) {
            #pragma unroll
            for (int cg = 0; cg < 6; ++cg) {
                float4 bv4 = *(const float4*)&bl1[cg * 16 + lk * 4];
                int pos = wv_ * 32 + pg * 16 + lr;
                f16x2 h01 = { (f16)(acc[pg][cg][0] + bv4.x), (f16)(acc[pg][cg][1] + bv4.y) };
                f16x2 h23 = { (f16)(acc[pg][cg][2] + bv4.z), (f16)(acc[pg][cg][3] + bv4.w) };
                uint2 st; st.x = hAsU(h01); st.y = hAsU(h23);
                *(uint2*)(Xsh + pos * 104 + cg * 16 + lk * 4) = st;
            }
        }
    } else {
        #pragma unroll
        for (int pg = 0; pg < 2; ++pg) {
            #pragma unroll
            for (int cg = 0; cg < 6; ++cg) {
                float bv = bl1[cg * 16 + lr];
                int ch = cg * 16 + lr;
                int pos = wv_ * 32 + pg * 16 + lk * 4;
                f16x2 h01 = { (f16)(acc[pg][cg][0] + bv), (f16)(acc[pg][cg][1] + bv) };
                f16x2 h23 = { (f16)(acc[pg][cg][2] + bv), (f16)(acc[pg][cg][3] + bv) };
                uint2 st; st.x = hAsU(h01); st.y = hAsU(h23);
                *(uint2*)(Xsh + ch * 520 + pos) = st;
            }
        }
    }
    __syncthreads();

    // ---- depthwise 3x3x3 SAME ----
    if (which < 2) {
        f16* slab = Xsh;
        unsigned* wdh = wdx;
        f16* outb = ((which == 0) ? qo : ko) + (size_t)b * 512 * 96;
        #pragma unroll
        for (int half = 0; half < 2; ++half) {
            if (half == 1 && tid >= 512) break;
            const int u = half * 1024 + tid;
            const int r = u / 24;
            const int g4 = u - r * 24;
            const int dd = r >> 3, hh = r & 7;
            const int col = g4 * 4;
            float mo[8][4];
            {
                float4 b0 = *(const float4*)&bld[col];
                #pragma unroll
                for (int w = 0; w < 8; ++w) {
                    mo[w][0] = b0.x; mo[w][1] = b0.y; mo[w][2] = b0.z; mo[w][3] = b0.w;
                }
            }
            #pragma unroll
            for (int kd = 0; kd < 3; ++kd) {
                const int d2 = dd + kd - 1;
                const bool vd = (unsigned)d2 < 8u;
                f16x2 pa[8][2];
                #pragma unroll
                for (int w = 0; w < 8; ++w) {
                    pa[w][0] = f16x2{0, 0}; pa[w][1] = f16x2{0, 0};
                }
                #pragma unroll
                for (int kh = 0; kh < 3; ++kh) {
                    const int h2 = hh + kh - 1;
                    const unsigned vm = (vd && ((unsigned)h2 < 8u)) ? 0xFFFFFFFFu : 0u;
                    const int base = (vm ? (d2 * 64 + h2 * 8) : 0) * 104 + col;
                    U2H in[8];
                    #pragma unroll
                    for (int w2 = 0; w2 < 8; ++w2)
                        in[w2].q = *(const uint2*)(slab + base + w2 * 104);
                    const int t0 = (kd * 3 + kh) * 3;
                    f16x2 wt0[2], wt1[2], wt2[2];
                    #pragma unroll
                    for (int p = 0; p < 2; ++p) {
                        wt0[p] = uAsH(wdh[(t0 + 0) * 48 + g4 * 2 + p] & vm);
                        wt1[p] = uAsH(wdh[(t0 + 1) * 48 + g4 * 2 + p] & vm);
                        wt2[p] = uAsH(wdh[(t0 + 2) * 48 + g4 * 2 + p] & vm);
                    }
                    #pragma unroll
                    for (int w = 0; w < 8; ++w) {
                        #pragma unroll
                        for (int p = 0; p < 2; ++p) {
                            f16x2 s = pa[w][p];
                            s = in[w].h[p] * wt1[p] + s;
                            if (w > 0) s = in[w - 1].h[p] * wt0[p] + s;
                            if (w < 7) s = in[w + 1].h[p] * wt2[p] + s;
                            pa[w][p] = s;
                        }
                    }
                }
                #pragma unroll
                for (int w = 0; w < 8; ++w)
                    #pragma unroll
                    for (int p = 0; p < 2; ++p) {
                        mo[w][2 * p]     += (float)pa[w][p].x;
                        mo[w][2 * p + 1] += (float)pa[w][p].y;
                    }
            }
            #pragma unroll
            for (int w = 0; w < 8; ++w) {
                f16x2 h0 = { (f16)mo[w][0], (f16)mo[w][1] };
                f16x2 h1 = { (f16)mo[w][2], (f16)mo[w][3] };
                uint2 st; st.x = hAsU(h0); st.y = hAsU(h1);
                *(uint2*)(outb + (size_t)(r * 8 + w) * 96 + col) = st;
            }
        }
    } else {
        f16* slab = Xsh;                       // [96][520]
        unsigned* wdp = wdx;
        f16* outb = vo + (size_t)b * 96 * 512;
        #pragma unroll
        for (int j = 0; j < 6; ++j) {
            int u = tid + j * 1024;
            int c = u >> 6, dh = u & 63;
            int dd = dh >> 3, hh2 = dh & 7;
            f16x2 A0[4], A1[4], A2[4];
            #pragma unroll
            for (int p = 0; p < 4; ++p) {
                A0[p] = f16x2{0, 0}; A1[p] = f16x2{0, 0}; A2[p] = f16x2{0, 0};
            }
            #pragma unroll
            for (int kd = 0; kd < 3; ++kd) {
                int d2 = dd + kd - 1;
                unsigned vd_ = ((unsigned)d2 < 8u) ? 0xFFFFFFFFu : 0u;
                #pragma unroll
                for (int kh = 0; kh < 3; ++kh) {
                    int h2 = hh2 + kh - 1;
                    unsigned vm = ((((unsigned)h2 < 8u) ? 0xFFFFFFFFu : 0u) & vd_);
                    int rowoff = vm ? ((d2 * 8 + h2) * 8) : 0;
                    uint4 rw = *(const uint4*)(slab + c * 520 + rowoff);
                    unsigned r0 = rw.x, r1 = rw.y, r2 = rw.z, r3 = rw.w;
                    unsigned ms0 = r0 << 16;
                    unsigned ms1 = (r1 << 16) | (r0 >> 16);
                    unsigned ms2 = (r2 << 16) | (r1 >> 16);
                    unsigned ms3 = (r3 << 16) | (r2 >> 16);
                    unsigned ms4 = r3 >> 16;
                    int t0 = kd * 9 + kh * 3;
                    f16x2 w0 = uAsH(wdp[c * 27 + t0]     & vm);
                    f16x2 w1 = uAsH(wdp[c * 27 + t0 + 1] & vm);
                    f16x2 w2 = uAsH(wdp[c * 27 + t0 + 2] & vm);
                    f16x2* acc2 = (kd == 0) ? A0 : ((kd == 1) ? A1 : A2);
                    acc2[0] = uAsH(ms0) * w0 + acc2[0];
                    acc2[1] = uAsH(ms1) * w0 + acc2[1];
                    acc2[2] = uAsH(ms2) * w0 + acc2[2];
                    acc2[3] = uAsH(ms3) * w0 + acc2[3];
                    acc2[0] = uAsH(r0) * w1 + acc2[0];
                    acc2[1] = uAsH(r1) * w1 + acc2[1];
                    acc2[2] = uAsH(r2) * w1 + acc2[2];
                    acc2[3] = uAsH(r3) * w1 + acc2[3];
                    acc2[0] = uAsH(ms1) * w2 + acc2[0];
                    acc2[1] = uAsH(ms2) * w2 + acc2[1];
                    acc2[2] = uAsH(ms3) * w2 + acc2[2];
                    acc2[3] = uAsH(ms4) * w2 + acc2[3];
                }
            }
            float bv = bld[c];
            unsigned ow[4];
            #pragma unroll
            for (int p = 0; p < 4; ++p) {
                float lo = (float)A0[p].x + (float)A1[p].x + (float)A2[p].x + bv;
                float hi = (float)A0[p].y + (float)A1[p].y + (float)A2[p].y + bv;
                f16x2 hp = { (f16)lo, (f16)hi };
                ow[p] = hAsU(hp);
            }
            *(uint4*)(outb + c * 512 + dh * 8) = make_uint4(ow[0], ow[1], ow[2], ow[3]);
        }
    }
}

// ---------------------------------------------------------------------------
// K3 v8: single-pass, 1024-thread blocks (16 waves = 4/SIMD; VGPR<=128 by
// co-residency). Wave = 32 q-rows (2 q-groups). kf read inline from Ksh
// (no hoist, saves 48 regs); vb[2][6] hoisted per tile (out of PV chain);
// qf streamed per q-group. grid 512.
// ---------------------------------------------------------------------------
__global__ __launch_bounds__(1024, 4) void k3_attn(
    const f16* __restrict__ qF, const f16* __restrict__ kF, const f16* __restrict__ vF,
    float* __restrict__ outp)
{
    __shared__ __align__(16) f16 Ksh[512 * 104];   // 106496 B
    __shared__ __align__(16) f16 Psh[16 * 1152];   // 16 waves x [16 q][72 k] = 36864 B

    const int tid = threadIdx.x;
    const int b = blockIdx.x;
    const int wv_ = tid >> 6, lane = tid & 63, lr = lane & 15, lk = lane >> 4;

    const f16* qg = qF + ((size_t)b * 512 + wv_ * 32) * 96;
    const f16* kg = kF + (size_t)b * 512 * 96;
    const f16* vg = vF + (size_t)b * 96 * 512;

    const float scl = 0.14724447f;   // log2(e)/sqrt(96), applied post-MFMA

    #pragma unroll
    for (int it = 0; it < 6; ++it) {
        int i = tid * 8 + it * 8192;
        int r = i / 96, c = i % 96;
        *(uint4*)(Ksh + r * 104 + c) = *(const uint4*)(kg + i);
    }
    __syncthreads();

    float sum_p[2] = {0.f, 0.f};
    f32x4 accO[2][6];
    #pragma unroll
    for (int qg2 = 0; qg2 < 2; ++qg2)
        #pragma unroll
        for (int cg = 0; cg < 6; ++cg) accO[qg2][cg] = f32x4{0.f, 0.f, 0.f, 0.f};

    f16* psw = Psh + wv_ * 1152;
    uint2* psw2 = (uint2*)psw;

    for (int t = 0; t < 8; ++t) {
        // hoist V fragments for this tile (kept OUT of the PV dep-chain)
        f16x8 vb[2][6];
        #pragma unroll
        for (int ks2 = 0; ks2 < 2; ++ks2)
            #pragma unroll
            for (int cg = 0; cg < 6; ++cg)
                vb[ks2][cg] = *(const f16x8*)(vg + (size_t)(cg * 16 + lr) * 512
                                                 + t * 64 + ks2 * 32 + lk * 8);
        #pragma unroll
        for (int qg2 = 0; qg2 < 2; ++qg2) {
            f16x8 qf3[3];
            #pragma unroll
            for (int ks3 = 0; ks3 < 3; ++ks3)
                qf3[ks3] = *(const f16x8*)(qg + (qg2 * 16 + lr) * 96 + ks3 * 32 + lk * 8);
            f32x4 sa[4];
            #pragma unroll
            for (int f = 0; f < 4; ++f) sa[f] = f32x4{0.f, 0.f, 0.f, 0.f};
            #pragma unroll
            for (int ks3 = 0; ks3 < 3; ++ks3)
                #pragma unroll
                for (int f = 0; f < 4; ++f) {
                    f16x8 kf = *(const f16x8*)(Ksh + (t * 64 + f * 16 + lr) * 104 + ks3 * 32 + lk * 8);
                    sa[f] = __builtin_amdgcn_mfma_f32_16x16x32_f16(kf, qf3[ks3], sa[f], 0, 0, 0);
                }
            #pragma unroll
            for (int f = 0; f < 4; ++f) {
                float e0 = __builtin_amdgcn_exp2f(sa[f][0] * scl);
                float e1 = __builtin_amdgcn_exp2f(sa[f][1] * scl);
                float e2 = __builtin_amdgcn_exp2f(sa[f][2] * scl);
                float e3 = __builtin_amdgcn_exp2f(sa[f][3] * scl);
                sum_p[qg2] += (e0 + e1) + (e2 + e3);
                uint2 pk;
                pk.x = pAsU(__builtin_amdgcn_cvt_pkrtz(e0, e1));
                pk.y = pAsU(__builtin_amdgcn_cvt_pkrtz(e2, e3));
                psw2[lr * 18 + f * 4 + lk] = pk;
            }
            #pragma unroll
            for (int ks2 = 0; ks2 < 2; ++ks2) {
                f16x8 pb = *(const f16x8*)(psw + lr * 72 + ks2 * 32 + lk * 8);
                #pragma unroll
                for (int cg = 0; cg < 6; ++cg)
                    accO[qg2][cg] = __builtin_amdgcn_mfma_f32_16x16x32_f16(
                        vb[ks2][cg], pb, accO[qg2][cg], 0, 0, 0);
            }
        }
    }
    #pragma unroll
    for (int qg2 = 0; qg2 < 2; ++qg2) {
        sum_p[qg2] += __shfl_xor(sum_p[qg2], 16);
        sum_p[qg2] += __shfl_xor(sum_p[qg2], 32);
    }

    #pragma unroll
    for (int qg2 = 0; qg2 < 2; ++qg2) {
        const float inv = 1.0f / sum_p[qg2];
        float* og = outp + ((size_t)b * 512 + wv_ * 32 + qg2 * 16 + lr) * 96;
        #pragma unroll
        for (int cg = 0; cg < 6; ++cg) {
            float4 o4 = make_float4(accO[qg2][cg][0] * inv, accO[qg2][cg][1] * inv,
                                    accO[qg2][cg][2] * inv, accO[qg2][cg][3] * inv);
            *(float4*)(og + cg * 16 + lk * 4) = o4;
        }
    }
}

extern "C" void kernel_launch(void* const* d_in, const int* in_sizes, int n_in,
                              void* d_out, int out_size, void* d_ws, size_t ws_size,
                              hipStream_t stream) {
    const float* x   = (const float*)d_in[0];
    const float* wq1 = (const float*)d_in[1];
    const float* bq1 = (const float*)d_in[2];
    const float* wk1 = (const float*)d_in[3];
    const float* bk1 = (const float*)d_in[4];
    const float* wv1 = (const float*)d_in[5];
    const float* bv1 = (const float*)d_in[6];
    const float* wqd = (const float*)d_in[7];
    const float* bqd = (const float*)d_in[8];
    const float* wkd = (const float*)d_in[9];
    const float* bkd = (const float*)d_in[10];
    const float* wvd = (const float*)d_in[11];
    const float* bvd = (const float*)d_in[12];

    f16* ws = (f16*)d_ws;
    f16* q = ws;
    f16* k = ws + PL;
    f16* v = ws + 2 * PL;

    k12_fused<<<dim3(512, 3), 1024, 0, stream>>>(x, wq1, bq1, wk1, bk1, wv1, bv1,
                                                 wqd, bqd, wkd, bkd, wvd, bvd, q, k, v);
    k3_attn<<<512, 1024, 0, stream>>>(q, k, v, (float*)d_out);
}

// Round 15
// 272.513 us; speedup vs baseline: 1.4743x; 1.4743x over previous
//
#include <hip/hip_runtime.h>
#include <math.h>

typedef _Float16 f16;
typedef _Float16 f16x2 __attribute__((ext_vector_type(2)));
typedef _Float16 f16x8 __attribute__((ext_vector_type(8)));
typedef __fp16 fp16x2 __attribute__((ext_vector_type(2)));
typedef float f32x4 __attribute__((ext_vector_type(4)));

union F2U { f16x2 h; fp16x2 p; unsigned u; };
union U2H { uint2 q; f16x2 h[2]; f16 f[4]; };
union U4H { uint4 q; f16x2 h[4]; f16 f[8]; };

__device__ __forceinline__ f16x2 uAsH(unsigned u) { F2U c; c.u = u; return c.h; }
__device__ __forceinline__ unsigned hAsU(f16x2 h) { F2U c; c.h = h; return c.u; }
__device__ __forceinline__ unsigned pAsU(fp16x2 p) { F2U c; c.p = p; return c.u; }

constexpr size_t PL = (size_t)512 * 512 * 96;

// ---------------------------------------------------------------------------
// K12 v6: round-13 structure, register demand trimmed below the 64-VGPR
// allocation 1024-thread kernels get: (a) GEMM B-fragments loaded per-MFMA
// (not hoisted x6); (b) q/k depthwise stencil split into two 4-output halves
// (in[6] uint2 + pa[4][2] + mo[4][4] ~ 45 regs peak). Kills the ~45 MB spill.
// grid (512 batch, 3 conv), block 1024 (16 waves).
// ---------------------------------------------------------------------------
__global__ __launch_bounds__(1024, 4) void k12_fused(
    const float* __restrict__ x,
    const float* __restrict__ wq1, const float* __restrict__ bq1,
    const float* __restrict__ wk1, const float* __restrict__ bk1,
    const float* __restrict__ wv1, const float* __restrict__ bv1,
    const float* __restrict__ wqd, const float* __restrict__ bqd,
    const float* __restrict__ wkd, const float* __restrict__ bkd,
    const float* __restrict__ wvd, const float* __restrict__ bvd,
    f16* __restrict__ qo, f16* __restrict__ ko, f16* __restrict__ vo)
{
    __shared__ __align__(16) char sm[137600];
    f16* Xsh = (f16*)sm;                       // [512][104] f16; overlaid post-GEMM
    f16* Wsh = (f16*)(sm + 106496);            // [96][104] f16 pointwise w
    unsigned* wdx = (unsigned*)(sm + 126464);  // q/k: [27][48] u32; v: [96][27] u32
    float* bl1 = (float*)(sm + 136832);        // [96] pointwise bias
    float* bld = (float*)(sm + 137216);        // [96] depthwise bias

    const int tid = threadIdx.x;
    const int b = blockIdx.x;
    const int which = blockIdx.y;
    const int wv_ = tid >> 6, lane = tid & 63, lr = lane & 15, lk = lane >> 4;

    const float* w1 = (which == 0) ? wq1 : ((which == 1) ? wk1 : wv1);
    const float* b1 = (which == 0) ? bq1 : ((which == 1) ? bk1 : bv1);
    const float* wd = (which == 0) ? wqd : ((which == 1) ? wkd : wvd);
    const float* bd = (which == 0) ? bqd : ((which == 1) ? bkd : bvd);

    // ---- stage x (f32->f16), pointwise w, depthwise w, biases ----
    const float* xb = x + (size_t)b * 512 * 96;
    #pragma unroll
    for (int it = 0; it < 12; ++it) {
        int i = (tid + it * 1024) * 4;
        float4 v4 = *(const float4*)(xb + i);
        int r = i / 96, c = i % 96;
        f16x2 h01 = { (f16)v4.x, (f16)v4.y };
        f16x2 h23 = { (f16)v4.z, (f16)v4.w };
        uint2 st; st.x = hAsU(h01); st.y = hAsU(h23);
        *(uint2*)(Xsh + r * 104 + c) = st;
    }
    #pragma unroll
    for (int it = 0; it < 3; ++it) {
        int i = (tid + it * 1024) * 4;
        if (i < 9216) {
            float4 v4 = *(const float4*)(w1 + i);
            int co = i / 96, ci = i % 96;
            f16x2 h01 = { (f16)v4.x, (f16)v4.y };
            f16x2 h23 = { (f16)v4.z, (f16)v4.w };
            uint2 st; st.x = hAsU(h01); st.y = hAsU(h23);
            *(uint2*)(Wsh + co * 104 + ci) = st;
        }
    }
    if (which < 2) {
        for (int ii = tid; ii < 2592; ii += 1024) {
            int c = ii / 27, t2 = ii % 27;
            ((f16*)wdx)[t2 * 96 + c] = (f16)wd[ii];
        }
    } else {
        for (int ii = tid; ii < 2592; ii += 1024) {
            int c = ii / 27, t2 = ii % 27;
            f16 hh = (f16)wd[ii];
            f16x2 hp = { hh, hh };
            wdx[c * 27 + t2] = hAsU(hp);
        }
    }
    if (tid < 96) { bl1[tid] = b1[tid]; bld[tid] = bd[tid]; }
    __syncthreads();

    // ---- pointwise GEMM: wave = 32 positions x 96 out-channels ----
    // B-fragments NOT hoisted (peak regs = acc48 + a4 + bfr4 < 64)
    f32x4 acc[2][6];
    #pragma unroll
    for (int pg = 0; pg < 2; ++pg)
        #pragma unroll
        for (int cg = 0; cg < 6; ++cg) acc[pg][cg] = f32x4{0.f, 0.f, 0.f, 0.f};

    if (which < 2) {
        #pragma unroll
        for (int ks = 0; ks < 3; ++ks) {
            #pragma unroll
            for (int pg = 0; pg < 2; ++pg) {
                f16x8 a = *(const f16x8*)(Xsh + (wv_ * 32 + pg * 16 + lr) * 104 + ks * 32 + lk * 8);
                #pragma unroll
                for (int cg = 0; cg < 6; ++cg) {
                    f16x8 bfr = *(const f16x8*)(Wsh + (cg * 16 + lr) * 104 + ks * 32 + lk * 8);
                    acc[pg][cg] = __builtin_amdgcn_mfma_f32_16x16x32_f16(bfr, a, acc[pg][cg], 0, 0, 0);
                }
            }
        }
    } else {
        #pragma unroll
        for (int ks = 0; ks < 3; ++ks) {
            #pragma unroll
            for (int pg = 0; pg < 2; ++pg) {
                f16x8 a = *(const f16x8*)(Xsh + (wv_ * 32 + pg * 16 + lr) * 104 + ks * 32 + lk * 8);
                #pragma unroll
                for (int cg = 0; cg < 6; ++cg) {
                    f16x8 bfr = *(const f16x8*)(Wsh + (cg * 16 + lr) * 104 + ks * 32 + lk * 8);
                    acc[pg][cg] = __builtin_amdgcn_mfma_f32_16x16x32_f16(a, bfr, acc[pg][cg], 0, 0, 0);
                }
            }
        }
    }
    __syncthreads();   // all Xsh reads done before overlay

    // ---- write GEMM out (+bias) over the slab ----
    if (which < 2) {
        #pragma unroll
        for (int pg = 0; pg < 2; ++pg) {
            #pragma unroll
            for (int cg = 0; cg < 6; ++cg) {
                float4 bv4 = *(const float4*)&bl1[cg * 16 + lk * 4];
                int pos = wv_ * 32 + pg * 16 + lr;
                f16x2 h01 = { (f16)(acc[pg][cg][0] + bv4.x), (f16)(acc[pg][cg][1] + bv4.y) };
                f16x2 h23 = { (f16)(acc[pg][cg][2] + bv4.z), (f16)(acc[pg][cg][3] + bv4.w) };
                uint2 st; st.x = hAsU(h01); st.y = hAsU(h23);
                *(uint2*)(Xsh + pos * 104 + cg * 16 + lk * 4) = st;
            }
        }
    } else {
        #pragma unroll
        for (int pg = 0; pg < 2; ++pg) {
            #pragma unroll
            for (int cg = 0; cg < 6; ++cg) {
                float bv = bl1[cg * 16 + lr];
                int ch = cg * 16 + lr;
                int pos = wv_ * 32 + pg * 16 + lk * 4;
                f16x2 h01 = { (f16)(acc[pg][cg][0] + bv), (f16)(acc[pg][cg][1] + bv) };
                f16x2 h23 = { (f16)(acc[pg][cg][2] + bv), (f16)(acc[pg][cg][3] + bv) };
                uint2 st; st.x = hAsU(h01); st.y = hAsU(h23);
                *(uint2*)(Xsh + ch * 520 + pos) = st;
            }
        }
    }
    __syncthreads();

    // ---- depthwise 3x3x3 SAME ----
    if (which < 2) {
        // unit = (w-row r=(d,h), 4-ch group g4), 1536 units; each unit runs
        // two 4-output half-passes (w-halves) to cap register pressure.
        f16* slab = Xsh;
        unsigned* wdh = wdx;
        f16* outb = ((which == 0) ? qo : ko) + (size_t)b * 512 * 96;
        #pragma unroll
        for (int half = 0; half < 2; ++half) {
            if (half == 1 && tid >= 512) break;
            const int u = half * 1024 + tid;
            const int r = u / 24;
            const int g4 = u - r * 24;
            const int dd = r >> 3, hh = r & 7;
            const int col = g4 * 4;
            #pragma unroll
            for (int wh = 0; wh < 2; ++wh) {
                float mo[4][4];
                {
                    float4 b0 = *(const float4*)&bld[col];
                    #pragma unroll
                    for (int wl = 0; wl < 4; ++wl) {
                        mo[wl][0] = b0.x; mo[wl][1] = b0.y; mo[wl][2] = b0.z; mo[wl][3] = b0.w;
                    }
                }
                #pragma unroll
                for (int kd = 0; kd < 3; ++kd) {
                    const int d2 = dd + kd - 1;
                    const bool vd = (unsigned)d2 < 8u;
                    f16x2 pa[4][2];
                    #pragma unroll
                    for (int wl = 0; wl < 4; ++wl) {
                        pa[wl][0] = f16x2{0, 0}; pa[wl][1] = f16x2{0, 0};
                    }
                    #pragma unroll
                    for (int kh = 0; kh < 3; ++kh) {
                        const int h2 = hh + kh - 1;
                        const unsigned vm = (vd && ((unsigned)h2 < 8u)) ? 0xFFFFFFFFu : 0u;
                        const int base = (vm ? (d2 * 64 + h2 * 8) : 0) * 104 + col;
                        U2H in[6];
                        #pragma unroll
                        for (int j = 0; j < 6; ++j) {
                            int gw = wh * 4 - 1 + j;
                            if ((unsigned)gw < 8u)
                                in[j].q = *(const uint2*)(slab + base + gw * 104);
                            else
                                in[j].q = make_uint2(0u, 0u);
                        }
                        const int t0 = (kd * 3 + kh) * 3;
                        f16x2 wt0[2], wt1[2], wt2[2];
                        #pragma unroll
                        for (int p = 0; p < 2; ++p) {
                            wt0[p] = uAsH(wdh[(t0 + 0) * 48 + g4 * 2 + p] & vm);
                            wt1[p] = uAsH(wdh[(t0 + 1) * 48 + g4 * 2 + p] & vm);
                            wt2[p] = uAsH(wdh[(t0 + 2) * 48 + g4 * 2 + p] & vm);
                        }
                        #pragma unroll
                        for (int wl = 0; wl < 4; ++wl) {
                            #pragma unroll
                            for (int p = 0; p < 2; ++p) {
                                f16x2 s = pa[wl][p];
                                s = in[wl].h[p]     * wt0[p] + s;
                                s = in[wl + 1].h[p] * wt1[p] + s;
                                s = in[wl + 2].h[p] * wt2[p] + s;
                                pa[wl][p] = s;
                            }
                        }
                    }
                    #pragma unroll
                    for (int wl = 0; wl < 4; ++wl)
                        #pragma unroll
                        for (int p = 0; p < 2; ++p) {
                            mo[wl][2 * p]     += (float)pa[wl][p].x;
                            mo[wl][2 * p + 1] += (float)pa[wl][p].y;
                        }
                }
                #pragma unroll
                for (int wl = 0; wl < 4; ++wl) {
                    f16x2 h0 = { (f16)mo[wl][0], (f16)mo[wl][1] };
                    f16x2 h1 = { (f16)mo[wl][2], (f16)mo[wl][3] };
                    uint2 st; st.x = hAsU(h0); st.y = hAsU(h1);
                    *(uint2*)(outb + (size_t)(r * 8 + wh * 4 + wl) * 96 + col) = st;
                }
            }
        }
    } else {
        f16* slab = Xsh;                       // [96][520]
        unsigned* wdp = wdx;
        f16* outb = vo + (size_t)b * 96 * 512;
        #pragma unroll
        for (int j = 0; j < 6; ++j) {
            int u = tid + j * 1024;
            int c = u >> 6, dh = u & 63;
            int dd = dh >> 3, hh2 = dh & 7;
            f16x2 A0[4], A1[4], A2[4];
            #pragma unroll
            for (int p = 0; p < 4; ++p) {
                A0[p] = f16x2{0, 0}; A1[p] = f16x2{0, 0}; A2[p] = f16x2{0, 0};
            }
            #pragma unroll
            for (int kd = 0; kd < 3; ++kd) {
                int d2 = dd + kd - 1;
                unsigned vd_ = ((unsigned)d2 < 8u) ? 0xFFFFFFFFu : 0u;
                #pragma unroll
                for (int kh = 0; kh < 3; ++kh) {
                    int h2 = hh2 + kh - 1;
                    unsigned vm = ((((unsigned)h2 < 8u) ? 0xFFFFFFFFu : 0u) & vd_);
                    int rowoff = vm ? ((d2 * 8 + h2) * 8) : 0;
                    uint4 rw = *(const uint4*)(slab + c * 520 + rowoff);
                    unsigned r0 = rw.x, r1 = rw.y, r2 = rw.z, r3 = rw.w;
                    unsigned ms0 = r0 << 16;
                    unsigned ms1 = (r1 << 16) | (r0 >> 16);
                    unsigned ms2 = (r2 << 16) | (r1 >> 16);
                    unsigned ms3 = (r3 << 16) | (r2 >> 16);
                    unsigned ms4 = r3 >> 16;
                    int t0 = kd * 9 + kh * 3;
                    f16x2 w0 = uAsH(wdp[c * 27 + t0]     & vm);
                    f16x2 w1 = uAsH(wdp[c * 27 + t0 + 1] & vm);
                    f16x2 w2 = uAsH(wdp[c * 27 + t0 + 2] & vm);
                    f16x2* acc2 = (kd == 0) ? A0 : ((kd == 1) ? A1 : A2);
                    acc2[0] = uAsH(ms0) * w0 + acc2[0];
                    acc2[1] = uAsH(ms1) * w0 + acc2[1];
                    acc2[2] = uAsH(ms2) * w0 + acc2[2];
                    acc2[3] = uAsH(ms3) * w0 + acc2[3];
                    acc2[0] = uAsH(r0) * w1 + acc2[0];
                    acc2[1] = uAsH(r1) * w1 + acc2[1];
                    acc2[2] = uAsH(r2) * w1 + acc2[2];
                    acc2[3] = uAsH(r3) * w1 + acc2[3];
                    acc2[0] = uAsH(ms1) * w2 + acc2[0];
                    acc2[1] = uAsH(ms2) * w2 + acc2[1];
                    acc2[2] = uAsH(ms3) * w2 + acc2[2];
                    acc2[3] = uAsH(ms4) * w2 + acc2[3];
                }
            }
            float bv = bld[c];
            unsigned ow[4];
            #pragma unroll
            for (int p = 0; p < 4; ++p) {
                float lo = (float)A0[p].x + (float)A1[p].x + (float)A2[p].x + bv;
                float hi = (float)A0[p].y + (float)A1[p].y + (float)A2[p].y + bv;
                f16x2 hp = { (f16)lo, (f16)hi };
                ow[p] = hAsU(hp);
            }
            *(uint4*)(outb + c * 512 + dh * 8) = make_uint4(ow[0], ow[1], ow[2], ow[3]);
        }
    }
}

// ---------------------------------------------------------------------------
// K3 v7 (round-13 verbatim — the ~80 us config): single-pass softmax,
// kf + vb hoisted per tile, qf streamed per q-group, 512 threads (8 waves).
// ---------------------------------------------------------------------------
__global__ __launch_bounds__(512) void k3_attn(
    const f16* __restrict__ qF, const f16* __restrict__ kF, const f16* __restrict__ vF,
    float* __restrict__ outp)
{
    __shared__ __align__(16) f16 Ksh[512 * 104];   // 106496 B
    __shared__ __align__(16) f16 Psh[8 * 1152];    // 8 waves x [16 q][72 k]

    const int tid = threadIdx.x;
    const int b = blockIdx.x;
    const int wv_ = tid >> 6, lane = tid & 63, lr = lane & 15, lk = lane >> 4;

    const f16* qg = qF + ((size_t)b * 512 + wv_ * 64) * 96;
    const f16* kg = kF + (size_t)b * 512 * 96;
    const f16* vg = vF + (size_t)b * 96 * 512;

    const float scl = 0.14724447f;   // log2(e)/sqrt(96), applied post-MFMA

    #pragma unroll
    for (int it = 0; it < 12; ++it) {
        int i = tid * 8 + it * 4096;
        int r = i / 96, c = i % 96;
        *(uint4*)(Ksh + r * 104 + c) = *(const uint4*)(kg + i);
    }
    __syncthreads();

    float sum_p[4] = {0.f, 0.f, 0.f, 0.f};
    f32x4 accO[4][6];
    #pragma unroll
    for (int qg2 = 0; qg2 < 4; ++qg2)
        #pragma unroll
        for (int cg = 0; cg < 6; ++cg) accO[qg2][cg] = f32x4{0.f, 0.f, 0.f, 0.f};

    f16* psw = Psh + wv_ * 1152;
    uint2* psw2 = (uint2*)psw;

    for (int t = 0; t < 8; ++t) {
        f16x8 kf[3][4];
        #pragma unroll
        for (int ks3 = 0; ks3 < 3; ++ks3)
            #pragma unroll
            for (int f = 0; f < 4; ++f)
                kf[ks3][f] = *(const f16x8*)(Ksh + (t * 64 + f * 16 + lr) * 104 + ks3 * 32 + lk * 8);
        f16x8 vb[2][6];
        #pragma unroll
        for (int ks2 = 0; ks2 < 2; ++ks2)
            #pragma unroll
            for (int cg = 0; cg < 6; ++cg)
                vb[ks2][cg] = *(const f16x8*)(vg + (size_t)(cg * 16 + lr) * 512
                                                 + t * 64 + ks2 * 32 + lk * 8);
        #pragma unroll
        for (int qg2 = 0; qg2 < 4; ++qg2) {
            f16x8 qf3[3];
            #pragma unroll
            for (int ks3 = 0; ks3 < 3; ++ks3)
                qf3[ks3] = *(const f16x8*)(qg + (qg2 * 16 + lr) * 96 + ks3 * 32 + lk * 8);
            f32x4 sa[4];
            #pragma unroll
            for (int f = 0; f < 4; ++f) sa[f] = f32x4{0.f, 0.f, 0.f, 0.f};
            #pragma unroll
            for (int ks3 = 0; ks3 < 3; ++ks3)
                #pragma unroll
                for (int f = 0; f < 4; ++f)
                    sa[f] = __builtin_amdgcn_mfma_f32_16x16x32_f16(kf[ks3][f], qf3[ks3], sa[f], 0, 0, 0);
            #pragma unroll
            for (int f = 0; f < 4; ++f) {
                float e0 = __builtin_amdgcn_exp2f(sa[f][0] * scl);
                float e1 = __builtin_amdgcn_exp2f(sa[f][1] * scl);
                float e2 = __builtin_amdgcn_exp2f(sa[f][2] * scl);
                float e3 = __builtin_amdgcn_exp2f(sa[f][3] * scl);
                sum_p[qg2] += (e0 + e1) + (e2 + e3);
                uint2 pk;
                pk.x = pAsU(__builtin_amdgcn_cvt_pkrtz(e0, e1));
                pk.y = pAsU(__builtin_amdgcn_cvt_pkrtz(e2, e3));
                psw2[lr * 18 + f * 4 + lk] = pk;
            }
            #pragma unroll
            for (int ks2 = 0; ks2 < 2; ++ks2) {
                f16x8 pb = *(const f16x8*)(psw + lr * 72 + ks2 * 32 + lk * 8);
                #pragma unroll
                for (int cg = 0; cg < 6; ++cg)
                    accO[qg2][cg] = __builtin_amdgcn_mfma_f32_16x16x32_f16(
                        vb[ks2][cg], pb, accO[qg2][cg], 0, 0, 0);
            }
        }
    }
    #pragma unroll
    for (int qg2 = 0; qg2 < 4; ++qg2) {
        sum_p[qg2] += __shfl_xor(sum_p[qg2], 16);
        sum_p[qg2] += __shfl_xor(sum_p[qg2], 32);
    }

    #pragma unroll
    for (int qg2 = 0; qg2 < 4; ++qg2) {
        const float inv = 1.0f / sum_p[qg2];
        float* og = outp + ((size_t)b * 512 + wv_ * 64 + qg2 * 16 + lr) * 96;
        #pragma unroll
        for (int cg = 0; cg < 6; ++cg) {
            float4 o4 = make_float4(accO[qg2][cg][0] * inv, accO[qg2][cg][1] * inv,
                                    accO[qg2][cg][2] * inv, accO[qg2][cg][3] * inv);
            *(float4*)(og + cg * 16 + lk * 4) = o4;
        }
    }
}

extern "C" void kernel_launch(void* const* d_in, const int* in_sizes, int n_in,
                              void* d_out, int out_size, void* d_ws, size_t ws_size,
                              hipStream_t stream) {
    const float* x   = (const float*)d_in[0];
    const float* wq1 = (const float*)d_in[1];
    const float* bq1 = (const float*)d_in[2];
    const float* wk1 = (const float*)d_in[3];
    const float* bk1 = (const float*)d_in[4];
    const float* wv1 = (const float*)d_in[5];
    const float* bv1 = (const float*)d_in[6];
    const float* wqd = (const float*)d_in[7];
    const float* bqd = (const float*)d_in[8];
    const float* wkd = (const float*)d_in[9];
    const float* bkd = (const float*)d_in[10];
    const float* wvd = (const float*)d_in[11];
    const float* bvd = (const float*)d_in[12];

    f16* ws = (f16*)d_ws;
    f16* q = ws;
    f16* k = ws + PL;
    f16* v = ws + 2 * PL;

    k12_fused<<<dim3(512, 3), 1024, 0, stream>>>(x, wq1, bq1, wk1, bk1, wv1, bv1,
                                                 wqd, bqd, wkd, bkd, wvd, bvd, q, k, v);
    k3_attn<<<512, 512, 0, stream>>>(q, k, v, (float*)d_out);
}

// Round 16
// 258.587 us; speedup vs baseline: 1.5537x; 1.0539x over previous
//
#include <hip/hip_runtime.h>
#include <math.h>

typedef _Float16 f16;
typedef _Float16 f16x2 __attribute__((ext_vector_type(2)));
typedef _Float16 f16x8 __attribute__((ext_vector_type(8)));
typedef __fp16 fp16x2 __attribute__((ext_vector_type(2)));
typedef float f32x4 __attribute__((ext_vector_type(4)));

union F2U { f16x2 h; fp16x2 p; unsigned u; };
union U2H { uint2 q; f16x2 h[2]; f16 f[4]; };
union U4H { uint4 q; f16x2 h[4]; f16 f[8]; };
union V8H { f16x8 v; f16x2 h[4]; f16 f[8]; };

__device__ __forceinline__ f16x2 uAsH(unsigned u) { F2U c; c.u = u; return c.h; }
__device__ __forceinline__ unsigned hAsU(f16x2 h) { F2U c; c.h = h; return c.u; }
__device__ __forceinline__ unsigned pAsU(fp16x2 p) { F2U c; c.p = p; return c.u; }

// load 8 consecutive f32 from global, convert to f16x8
__device__ __forceinline__ f16x8 ld8cvt(const float* p) {
    float4 a = *(const float4*)p;
    float4 b = *(const float4*)(p + 4);
    V8H r;
    r.f[0] = (f16)a.x; r.f[1] = (f16)a.y; r.f[2] = (f16)a.z; r.f[3] = (f16)a.w;
    r.f[4] = (f16)b.x; r.f[5] = (f16)b.y; r.f[6] = (f16)b.z; r.f[7] = (f16)b.w;
    return r.v;
}

constexpr size_t PL = (size_t)512 * 512 * 96;

// ---------------------------------------------------------------------------
// K12 v7: channel-split fused pointwise+depthwise. grid (512 b, 3 conv,
// 2 ch-half), block 512 (8 waves). Per block: 48 output channels.
// A (x) and W fragments straight from global (inline f32->f16); GEMM out
// (+bias) to a [512][60] (q/k) or [48][520] (v) LDS slab; round-13 depthwise.
// LDS ~74 KB -> 2 blocks/CU. No x staging, no spill (512 thr).
// Outputs: q,k [b][n][c]; v [b][c][n].
// ---------------------------------------------------------------------------
__global__ __launch_bounds__(512) void k12_fused(
    const float* __restrict__ x,
    const float* __restrict__ wq1, const float* __restrict__ bq1,
    const float* __restrict__ wk1, const float* __restrict__ bk1,
    const float* __restrict__ wv1, const float* __restrict__ bv1,
    const float* __restrict__ wqd, const float* __restrict__ bqd,
    const float* __restrict__ wkd, const float* __restrict__ bkd,
    const float* __restrict__ wvd, const float* __restrict__ bvd,
    f16* __restrict__ qo, f16* __restrict__ ko, f16* __restrict__ vo)
{
    __shared__ __align__(16) char sm[74400];

    const int tid = threadIdx.x;
    const int b = blockIdx.x;
    const int which = blockIdx.y;
    const int chalf = blockIdx.z;
    const int ch0 = chalf * 48;
    const int wv_ = tid >> 6, lane = tid & 63, lr = lane & 15, lk = lane >> 4;

    const float* w1 = (which == 0) ? wq1 : ((which == 1) ? wk1 : wv1);
    const float* b1 = (which == 0) ? bq1 : ((which == 1) ? bk1 : bv1);
    const float* wd = (which == 0) ? wqd : ((which == 1) ? wkd : wvd);
    const float* bd = (which == 0) ? bqd : ((which == 1) ? bkd : bvd);
    const float* xb = x + (size_t)b * 512 * 96;

    if (which < 2) {
        f16*      slab = (f16*)sm;                 // [512][60] GEMM out
        f16*      Wsh  = (f16*)(sm + 61440);       // [48][104] pointwise w
        unsigned* wdh  = (unsigned*)(sm + 71424);  // [27][24] u32 = [27][48] f16
        float*    bl1  = (float*)(sm + 74016);     // [48]
        float*    bld  = (float*)(sm + 74208);     // [48]

        // stage W (rows ch0..ch0+47), depthwise w, biases
        #pragma unroll
        for (int it = 0; it < 3; ++it) {
            int g = tid + it * 512;
            if (g < 1152) {
                int i = g * 4;
                int co = i / 96, ci = i % 96;
                float4 v4 = *(const float4*)(w1 + (size_t)(ch0 + co) * 96 + ci);
                f16x2 h01 = { (f16)v4.x, (f16)v4.y };
                f16x2 h23 = { (f16)v4.z, (f16)v4.w };
                uint2 st; st.x = hAsU(h01); st.y = hAsU(h23);
                *(uint2*)(Wsh + co * 104 + ci) = st;
            }
        }
        for (int ii = tid; ii < 1296; ii += 512) {
            int lc = ii / 27, t2 = ii % 27;
            ((f16*)wdh)[t2 * 48 + lc] = (f16)wd[(ch0 + lc) * 27 + t2];
        }
        if (tid < 48) { bl1[tid] = b1[ch0 + tid]; bld[tid] = bd[ch0 + tid]; }
        __syncthreads();

        // GEMM (swapped: C quad = out-ch). A from global, W from LDS.
        f32x4 acc[4][3];
        #pragma unroll
        for (int pg = 0; pg < 4; ++pg)
            #pragma unroll
            for (int cg = 0; cg < 3; ++cg) acc[pg][cg] = f32x4{0.f, 0.f, 0.f, 0.f};
        #pragma unroll
        for (int ks = 0; ks < 3; ++ks) {
            f16x8 bfr[3];
            #pragma unroll
            for (int cg = 0; cg < 3; ++cg)
                bfr[cg] = *(const f16x8*)(Wsh + (cg * 16 + lr) * 104 + ks * 32 + lk * 8);
            #pragma unroll
            for (int pg = 0; pg < 4; ++pg) {
                f16x8 a = ld8cvt(xb + (size_t)(wv_ * 64 + pg * 16 + lr) * 96 + ks * 32 + lk * 8);
                #pragma unroll
                for (int cg = 0; cg < 3; ++cg)
                    acc[pg][cg] = __builtin_amdgcn_mfma_f32_16x16x32_f16(bfr[cg], a, acc[pg][cg], 0, 0, 0);
            }
        }
        __syncthreads();

        // writeback (+bias): slab[pos][ch-quad], stride 60
        #pragma unroll
        for (int pg = 0; pg < 4; ++pg) {
            int pos = wv_ * 64 + pg * 16 + lr;
            #pragma unroll
            for (int cg = 0; cg < 3; ++cg) {
                float4 bv4 = *(const float4*)&bl1[cg * 16 + lk * 4];
                f16x2 h01 = { (f16)(acc[pg][cg][0] + bv4.x), (f16)(acc[pg][cg][1] + bv4.y) };
                f16x2 h23 = { (f16)(acc[pg][cg][2] + bv4.z), (f16)(acc[pg][cg][3] + bv4.w) };
                uint2 st; st.x = hAsU(h01); st.y = hAsU(h23);
                *(uint2*)(slab + pos * 60 + cg * 16 + lk * 4) = st;
            }
        }
        __syncthreads();

        // depthwise: 768 units = 64 (d,h)-rows x 12 4-ch groups
        f16* outb = ((which == 0) ? qo : ko) + (size_t)b * 512 * 96;
        #pragma unroll
        for (int half = 0; half < 2; ++half) {
            if (half == 1 && tid >= 256) break;
            const int u = half * 512 + tid;
            const int r = u / 12;
            const int g4 = u - r * 12;
            const int dd = r >> 3, hh = r & 7;
            const int col = g4 * 4;
            float mo[8][4];
            {
                float4 b0 = *(const float4*)&bld[col];
                #pragma unroll
                for (int w = 0; w < 8; ++w) {
                    mo[w][0] = b0.x; mo[w][1] = b0.y; mo[w][2] = b0.z; mo[w][3] = b0.w;
                }
            }
            #pragma unroll
            for (int kd = 0; kd < 3; ++kd) {
                const int d2 = dd + kd - 1;
                const bool vd = (unsigned)d2 < 8u;
                f16x2 pa[8][2];
                #pragma unroll
                for (int w = 0; w < 8; ++w) {
                    pa[w][0] = f16x2{0, 0}; pa[w][1] = f16x2{0, 0};
                }
                #pragma unroll
                for (int kh = 0; kh < 3; ++kh) {
                    const int h2 = hh + kh - 1;
                    const unsigned vm = (vd && ((unsigned)h2 < 8u)) ? 0xFFFFFFFFu : 0u;
                    const int base = (vm ? (d2 * 64 + h2 * 8) : 0) * 60 + col;
                    U2H in[8];
                    #pragma unroll
                    for (int w2 = 0; w2 < 8; ++w2)
                        in[w2].q = *(const uint2*)(slab + base + w2 * 60);
                    const int t0 = (kd * 3 + kh) * 3;
                    f16x2 wt0[2], wt1[2], wt2[2];
                    #pragma unroll
                    for (int p = 0; p < 2; ++p) {
                        wt0[p] = uAsH(wdh[(t0 + 0) * 24 + g4 * 2 + p] & vm);
                        wt1[p] = uAsH(wdh[(t0 + 1) * 24 + g4 * 2 + p] & vm);
                        wt2[p] = uAsH(wdh[(t0 + 2) * 24 + g4 * 2 + p] & vm);
                    }
                    #pragma unroll
                    for (int w = 0; w < 8; ++w) {
                        #pragma unroll
                        for (int p = 0; p < 2; ++p) {
                            f16x2 s = pa[w][p];
                            s = in[w].h[p] * wt1[p] + s;
                            if (w > 0) s = in[w - 1].h[p] * wt0[p] + s;
                            if (w < 7) s = in[w + 1].h[p] * wt2[p] + s;
                            pa[w][p] = s;
                        }
                    }
                }
                #pragma unroll
                for (int w = 0; w < 8; ++w)
                    #pragma unroll
                    for (int p = 0; p < 2; ++p) {
                        mo[w][2 * p]     += (float)pa[w][p].x;
                        mo[w][2 * p + 1] += (float)pa[w][p].y;
                    }
            }
            #pragma unroll
            for (int w = 0; w < 8; ++w) {
                f16x2 h0 = { (f16)mo[w][0], (f16)mo[w][1] };
                f16x2 h1 = { (f16)mo[w][2], (f16)mo[w][3] };
                uint2 st; st.x = hAsU(h0); st.y = hAsU(h1);
                *(uint2*)(outb + (size_t)(r * 8 + w) * 96 + ch0 + col) = st;
            }
        }
    } else {
        f16*      Vsh = (f16*)sm;                  // [48][520] GEMM out
        f16*      Wsh = (f16*)(sm + 49920);        // [48][104]
        unsigned* wdp = (unsigned*)(sm + 59904);   // [48][27] {w,w} pairs
        float*    bl1 = (float*)(sm + 65088);      // [48]
        float*    bld = (float*)(sm + 65280);      // [48]

        #pragma unroll
        for (int it = 0; it < 3; ++it) {
            int g = tid + it * 512;
            if (g < 1152) {
                int i = g * 4;
                int co = i / 96, ci = i % 96;
                float4 v4 = *(const float4*)(w1 + (size_t)(ch0 + co) * 96 + ci);
                f16x2 h01 = { (f16)v4.x, (f16)v4.y };
                f16x2 h23 = { (f16)v4.z, (f16)v4.w };
                uint2 st; st.x = hAsU(h01); st.y = hAsU(h23);
                *(uint2*)(Wsh + co * 104 + ci) = st;
            }
        }
        for (int ii = tid; ii < 1296; ii += 512) {
            int lc = ii / 27, t2 = ii % 27;
            f16 hh = (f16)wd[(ch0 + lc) * 27 + t2];
            f16x2 hp = { hh, hh };
            wdp[lc * 27 + t2] = hAsU(hp);
        }
        if (tid < 48) { bl1[tid] = b1[ch0 + tid]; bld[tid] = bd[ch0 + tid]; }
        __syncthreads();

        // GEMM (unswapped: C quad = positions). A from global, W from LDS.
        f32x4 acc[4][3];
        #pragma unroll
        for (int pg = 0; pg < 4; ++pg)
            #pragma unroll
            for (int cg = 0; cg < 3; ++cg) acc[pg][cg] = f32x4{0.f, 0.f, 0.f, 0.f};
        #pragma unroll
        for (int ks = 0; ks < 3; ++ks) {
            f16x8 bfr[3];
            #pragma unroll
            for (int cg = 0; cg < 3; ++cg)
                bfr[cg] = *(const f16x8*)(Wsh + (cg * 16 + lr) * 104 + ks * 32 + lk * 8);
            #pragma unroll
            for (int pg = 0; pg < 4; ++pg) {
                f16x8 a = ld8cvt(xb + (size_t)(wv_ * 64 + pg * 16 + lr) * 96 + ks * 32 + lk * 8);
                #pragma unroll
                for (int cg = 0; cg < 3; ++cg)
                    acc[pg][cg] = __builtin_amdgcn_mfma_f32_16x16x32_f16(a, bfr[cg], acc[pg][cg], 0, 0, 0);
            }
        }
        __syncthreads();

        // writeback [ch][pos], stride 520; pos quad = lk*4+reg
        #pragma unroll
        for (int pg = 0; pg < 4; ++pg) {
            int pos = wv_ * 64 + pg * 16 + lk * 4;
            #pragma unroll
            for (int cg = 0; cg < 3; ++cg) {
                float bv = bl1[cg * 16 + lr];
                int lc = cg * 16 + lr;
                f16x2 h01 = { (f16)(acc[pg][cg][0] + bv), (f16)(acc[pg][cg][1] + bv) };
                f16x2 h23 = { (f16)(acc[pg][cg][2] + bv), (f16)(acc[pg][cg][3] + bv) };
                uint2 st; st.x = hAsU(h01); st.y = hAsU(h23);
                *(uint2*)(Vsh + lc * 520 + pos) = st;
            }
        }
        __syncthreads();

        // depthwise shift-register: 3072 units = 48 ch x 64 octets
        f16* outb = vo + (size_t)b * 96 * 512;
        #pragma unroll
        for (int j = 0; j < 6; ++j) {
            int u = tid + j * 512;
            int c = u >> 6, dh = u & 63;
            int dd = dh >> 3, hh2 = dh & 7;
            f16x2 A0[4], A1[4], A2[4];
            #pragma unroll
            for (int p = 0; p < 4; ++p) {
                A0[p] = f16x2{0, 0}; A1[p] = f16x2{0, 0}; A2[p] = f16x2{0, 0};
            }
            #pragma unroll
            for (int kd = 0; kd < 3; ++kd) {
                int d2 = dd + kd - 1;
                unsigned vd_ = ((unsigned)d2 < 8u) ? 0xFFFFFFFFu : 0u;
                #pragma unroll
                for (int kh = 0; kh < 3; ++kh) {
                    int h2 = hh2 + kh - 1;
                    unsigned vm = ((((unsigned)h2 < 8u) ? 0xFFFFFFFFu : 0u) & vd_);
                    int rowoff = vm ? ((d2 * 8 + h2) * 8) : 0;
                    uint4 rw = *(const uint4*)(Vsh + c * 520 + rowoff);
                    unsigned r0 = rw.x, r1 = rw.y, r2 = rw.z, r3 = rw.w;
                    unsigned ms0 = r0 << 16;
                    unsigned ms1 = (r1 << 16) | (r0 >> 16);
                    unsigned ms2 = (r2 << 16) | (r1 >> 16);
                    unsigned ms3 = (r3 << 16) | (r2 >> 16);
                    unsigned ms4 = r3 >> 16;
                    int t0 = kd * 9 + kh * 3;
                    f16x2 w0 = uAsH(wdp[c * 27 + t0]     & vm);
                    f16x2 w1 = uAsH(wdp[c * 27 + t0 + 1] & vm);
                    f16x2 w2 = uAsH(wdp[c * 27 + t0 + 2] & vm);
                    f16x2* acc2 = (kd == 0) ? A0 : ((kd == 1) ? A1 : A2);
                    acc2[0] = uAsH(ms0) * w0 + acc2[0];
                    acc2[1] = uAsH(ms1) * w0 + acc2[1];
                    acc2[2] = uAsH(ms2) * w0 + acc2[2];
                    acc2[3] = uAsH(ms3) * w0 + acc2[3];
                    acc2[0] = uAsH(r0) * w1 + acc2[0];
                    acc2[1] = uAsH(r1) * w1 + acc2[1];
                    acc2[2] = uAsH(r2) * w1 + acc2[2];
                    acc2[3] = uAsH(r3) * w1 + acc2[3];
                    acc2[0] = uAsH(ms1) * w2 + acc2[0];
                    acc2[1] = uAsH(ms2) * w2 + acc2[1];
                    acc2[2] = uAsH(ms3) * w2 + acc2[2];
                    acc2[3] = uAsH(ms4) * w2 + acc2[3];
                }
            }
            float bv = bld[c];
            unsigned ow[4];
            #pragma unroll
            for (int p = 0; p < 4; ++p) {
                float lo = (float)A0[p].x + (float)A1[p].x + (float)A2[p].x + bv;
                float hi = (float)A0[p].y + (float)A1[p].y + (float)A2[p].y + bv;
                f16x2 hp = { (f16)lo, (f16)hi };
                ow[p] = hAsU(hp);
            }
            *(uint4*)(outb + (size_t)(ch0 + c) * 512 + dh * 8) = make_uint4(ow[0], ow[1], ow[2], ow[3]);
        }
    }
}

// ---------------------------------------------------------------------------
// K3 v7 (unchanged): single-pass softmax, kf + vb hoisted per tile,
// qf streamed per q-group, 512 threads (8 waves x 64 q-rows). grid 512.
// ---------------------------------------------------------------------------
__global__ __launch_bounds__(512) void k3_attn(
    const f16* __restrict__ qF, const f16* __restrict__ kF, const f16* __restrict__ vF,
    float* __restrict__ outp)
{
    __shared__ __align__(16) f16 Ksh[512 * 104];   // 106496 B
    __shared__ __align__(16) f16 Psh[8 * 1152];    // 8 waves x [16 q][72 k]

    const int tid = threadIdx.x;
    const int b = blockIdx.x;
    const int wv_ = tid >> 6, lane = tid & 63, lr = lane & 15, lk = lane >> 4;

    const f16* qg = qF + ((size_t)b * 512 + wv_ * 64) * 96;
    const f16* kg = kF + (size_t)b * 512 * 96;
    const f16* vg = vF + (size_t)b * 96 * 512;

    const float scl = 0.14724447f;   // log2(e)/sqrt(96), applied post-MFMA

    #pragma unroll
    for (int it = 0; it < 12; ++it) {
        int i = tid * 8 + it * 4096;
        int r = i / 96, c = i % 96;
        *(uint4*)(Ksh + r * 104 + c) = *(const uint4*)(kg + i);
    }
    __syncthreads();

    float sum_p[4] = {0.f, 0.f, 0.f, 0.f};
    f32x4 accO[4][6];
    #pragma unroll
    for (int qg2 = 0; qg2 < 4; ++qg2)
        #pragma unroll
        for (int cg = 0; cg < 6; ++cg) accO[qg2][cg] = f32x4{0.f, 0.f, 0.f, 0.f};

    f16* psw = Psh + wv_ * 1152;
    uint2* psw2 = (uint2*)psw;

    for (int t = 0; t < 8; ++t) {
        f16x8 kf[3][4];
        #pragma unroll
        for (int ks3 = 0; ks3 < 3; ++ks3)
            #pragma unroll
            for (int f = 0; f < 4; ++f)
                kf[ks3][f] = *(const f16x8*)(Ksh + (t * 64 + f * 16 + lr) * 104 + ks3 * 32 + lk * 8);
        f16x8 vb[2][6];
        #pragma unroll
        for (int ks2 = 0; ks2 < 2; ++ks2)
            #pragma unroll
            for (int cg = 0; cg < 6; ++cg)
                vb[ks2][cg] = *(const f16x8*)(vg + (size_t)(cg * 16 + lr) * 512
                                                 + t * 64 + ks2 * 32 + lk * 8);
        #pragma unroll
        for (int qg2 = 0; qg2 < 4; ++qg2) {
            f16x8 qf3[3];
            #pragma unroll
            for (int ks3 = 0; ks3 < 3; ++ks3)
                qf3[ks3] = *(const f16x8*)(qg + (qg2 * 16 + lr) * 96 + ks3 * 32 + lk * 8);
            f32x4 sa[4];
            #pragma unroll
            for (int f = 0; f < 4; ++f) sa[f] = f32x4{0.f, 0.f, 0.f, 0.f};
            #pragma unroll
            for (int ks3 = 0; ks3 < 3; ++ks3)
                #pragma unroll
                for (int f = 0; f < 4; ++f)
                    sa[f] = __builtin_amdgcn_mfma_f32_16x16x32_f16(kf[ks3][f], qf3[ks3], sa[f], 0, 0, 0);
            #pragma unroll
            for (int f = 0; f < 4; ++f) {
                float e0 = __builtin_amdgcn_exp2f(sa[f][0] * scl);
                float e1 = __builtin_amdgcn_exp2f(sa[f][1] * scl);
                float e2 = __builtin_amdgcn_exp2f(sa[f][2] * scl);
                float e3 = __builtin_amdgcn_exp2f(sa[f][3] * scl);
                sum_p[qg2] += (e0 + e1) + (e2 + e3);
                uint2 pk;
                pk.x = pAsU(__builtin_amdgcn_cvt_pkrtz(e0, e1));
                pk.y = pAsU(__builtin_amdgcn_cvt_pkrtz(e2, e3));
                psw2[lr * 18 + f * 4 + lk] = pk;
            }
            #pragma unroll
            for (int ks2 = 0; ks2 < 2; ++ks2) {
                f16x8 pb = *(const f16x8*)(psw + lr * 72 + ks2 * 32 + lk * 8);
                #pragma unroll
                for (int cg = 0; cg < 6; ++cg)
                    accO[qg2][cg] = __builtin_amdgcn_mfma_f32_16x16x32_f16(
                        vb[ks2][cg], pb, accO[qg2][cg], 0, 0, 0);
            }
        }
    }
    #pragma unroll
    for (int qg2 = 0; qg2 < 4; ++qg2) {
        sum_p[qg2] += __shfl_xor(sum_p[qg2], 16);
        sum_p[qg2] += __shfl_xor(sum_p[qg2], 32);
    }

    #pragma unroll
    for (int qg2 = 0; qg2 < 4; ++qg2) {
        const float inv = 1.0f / sum_p[qg2];
        float* og = outp + ((size_t)b * 512 + wv_ * 64 + qg2 * 16 + lr) * 96;
        #pragma unroll
        for (int cg = 0; cg < 6; ++cg) {
            float4 o4 = make_float4(accO[qg2][cg][0] * inv, accO[qg2][cg][1] * inv,
                                    accO[qg2][cg][2] * inv, accO[qg2][cg][3] * inv);
            *(float4*)(og + cg * 16 + lk * 4) = o4;
        }
    }
}

extern "C" void kernel_launch(void* const* d_in, const int* in_sizes, int n_in,
                              void* d_out, int out_size, void* d_ws, size_t ws_size,
                              hipStream_t stream) {
    const float* x   = (const float*)d_in[0];
    const float* wq1 = (const float*)d_in[1];
    const float* bq1 = (const float*)d_in[2];
    const float* wk1 = (const float*)d_in[3];
    const float* bk1 = (const float*)d_in[4];
    const float* wv1 = (const float*)d_in[5];
    const float* bv1 = (const float*)d_in[6];
    const float* wqd = (const float*)d_in[7];
    const float* bqd = (const float*)d_in[8];
    const float* wkd = (const float*)d_in[9];
    const float* bkd = (const float*)d_in[10];
    const float* wvd = (const float*)d_in[11];
    const float* bvd = (const float*)d_in[12];

    f16* ws = (f16*)d_ws;
    f16* q = ws;
    f16* k = ws + PL;
    f16* v = ws + 2 * PL;

    k12_fused<<<dim3(512, 3, 2), 512, 0, stream>>>(x, wq1, bq1, wk1, bk1, wv1, bv1,
                                                   wqd, bqd, wkd, bkd, wvd, bvd, q, k, v);
    k3_attn<<<512, 512, 0, stream>>>(q, k, v, (float*)d_out);
}

// Round 17
// 258.404 us; speedup vs baseline: 1.5548x; 1.0007x over previous
//
#include <hip/hip_runtime.h>
#include <math.h>

typedef _Float16 f16;
typedef _Float16 f16x2 __attribute__((ext_vector_type(2)));
typedef _Float16 f16x8 __attribute__((ext_vector_type(8)));
typedef __fp16 fp16x2 __attribute__((ext_vector_type(2)));
typedef float f32x4 __attribute__((ext_vector_type(4)));

union F2U { f16x2 h; fp16x2 p; unsigned u; };
union U2H { uint2 q; f16x2 h[2]; f16 f[4]; };
union U4H { uint4 q; f16x2 h[4]; f16 f[8]; };
union V8H { f16x8 v; f16x2 h[4]; f16 f[8]; };

__device__ __forceinline__ f16x2 uAsH(unsigned u) { F2U c; c.u = u; return c.h; }
__device__ __forceinline__ unsigned hAsU(f16x2 h) { F2U c; c.h = h; return c.u; }
__device__ __forceinline__ unsigned pAsU(fp16x2 p) { F2U c; c.p = p; return c.u; }

// load 8 consecutive f32 from global, convert to f16x8
__device__ __forceinline__ f16x8 ld8cvt(const float* p) {
    float4 a = *(const float4*)p;
    float4 b = *(const float4*)(p + 4);
    V8H r;
    r.f[0] = (f16)a.x; r.f[1] = (f16)a.y; r.f[2] = (f16)a.z; r.f[3] = (f16)a.w;
    r.f[4] = (f16)b.x; r.f[5] = (f16)b.y; r.f[6] = (f16)b.z; r.f[7] = (f16)b.w;
    return r.v;
}

constexpr size_t PL = (size_t)512 * 512 * 96;

// ---------------------------------------------------------------------------
// K12 v8: identical body to v7, but 1-D grid (3072) with batch-major decode
// so a batch's 6 blocks (3 convs x 2 ch-halves) are dispatch-ADJACENT:
// they run concurrently and share ONE HBM fetch of x[b] via the die-level L3
// (v7's layout put them 512 blocks apart -> 328 MB HBM refetch = the whole
// kernel's runtime). block 512 (8 waves), 48 output channels per block.
// Outputs: q,k [b][n][c]; v [b][c][n].
// ---------------------------------------------------------------------------
__global__ __launch_bounds__(512) void k12_fused(
    const float* __restrict__ x,
    const float* __restrict__ wq1, const float* __restrict__ bq1,
    const float* __restrict__ wk1, const float* __restrict__ bk1,
    const float* __restrict__ wv1, const float* __restrict__ bv1,
    const float* __restrict__ wqd, const float* __restrict__ bqd,
    const float* __restrict__ wkd, const float* __restrict__ bkd,
    const float* __restrict__ wvd, const float* __restrict__ bvd,
    f16* __restrict__ qo, f16* __restrict__ ko, f16* __restrict__ vo)
{
    __shared__ __align__(16) char sm[74400];

    const int tid = threadIdx.x;
    const int id = blockIdx.x;
    const int b = id / 6;
    const int r6 = id - b * 6;
    const int which = r6 >> 1;       // 0,0,1,1,2,2
    const int chalf = r6 & 1;
    const int ch0 = chalf * 48;
    const int wv_ = tid >> 6, lane = tid & 63, lr = lane & 15, lk = lane >> 4;

    const float* w1 = (which == 0) ? wq1 : ((which == 1) ? wk1 : wv1);
    const float* b1 = (which == 0) ? bq1 : ((which == 1) ? bk1 : bv1);
    const float* wd = (which == 0) ? wqd : ((which == 1) ? wkd : wvd);
    const float* bd = (which == 0) ? bqd : ((which == 1) ? bkd : bvd);
    const float* xb = x + (size_t)b * 512 * 96;

    if (which < 2) {
        f16*      slab = (f16*)sm;                 // [512][60] GEMM out
        f16*      Wsh  = (f16*)(sm + 61440);       // [48][104] pointwise w
        unsigned* wdh  = (unsigned*)(sm + 71424);  // [27][24] u32 = [27][48] f16
        float*    bl1  = (float*)(sm + 74016);     // [48]
        float*    bld  = (float*)(sm + 74208);     // [48]

        // stage W (rows ch0..ch0+47), depthwise w, biases
        #pragma unroll
        for (int it = 0; it < 3; ++it) {
            int g = tid + it * 512;
            if (g < 1152) {
                int i = g * 4;
                int co = i / 96, ci = i % 96;
                float4 v4 = *(const float4*)(w1 + (size_t)(ch0 + co) * 96 + ci);
                f16x2 h01 = { (f16)v4.x, (f16)v4.y };
                f16x2 h23 = { (f16)v4.z, (f16)v4.w };
                uint2 st; st.x = hAsU(h01); st.y = hAsU(h23);
                *(uint2*)(Wsh + co * 104 + ci) = st;
            }
        }
        for (int ii = tid; ii < 1296; ii += 512) {
            int lc = ii / 27, t2 = ii % 27;
            ((f16*)wdh)[t2 * 48 + lc] = (f16)wd[(ch0 + lc) * 27 + t2];
        }
        if (tid < 48) { bl1[tid] = b1[ch0 + tid]; bld[tid] = bd[ch0 + tid]; }
        __syncthreads();

        // GEMM (swapped: C quad = out-ch). A from global, W from LDS.
        f32x4 acc[4][3];
        #pragma unroll
        for (int pg = 0; pg < 4; ++pg)
            #pragma unroll
            for (int cg = 0; cg < 3; ++cg) acc[pg][cg] = f32x4{0.f, 0.f, 0.f, 0.f};
        #pragma unroll
        for (int ks = 0; ks < 3; ++ks) {
            f16x8 bfr[3];
            #pragma unroll
            for (int cg = 0; cg < 3; ++cg)
                bfr[cg] = *(const f16x8*)(Wsh + (cg * 16 + lr) * 104 + ks * 32 + lk * 8);
            #pragma unroll
            for (int pg = 0; pg < 4; ++pg) {
                f16x8 a = ld8cvt(xb + (size_t)(wv_ * 64 + pg * 16 + lr) * 96 + ks * 32 + lk * 8);
                #pragma unroll
                for (int cg = 0; cg < 3; ++cg)
                    acc[pg][cg] = __builtin_amdgcn_mfma_f32_16x16x32_f16(bfr[cg], a, acc[pg][cg], 0, 0, 0);
            }
        }
        __syncthreads();

        // writeback (+bias): slab[pos][ch-quad], stride 60
        #pragma unroll
        for (int pg = 0; pg < 4; ++pg) {
            int pos = wv_ * 64 + pg * 16 + lr;
            #pragma unroll
            for (int cg = 0; cg < 3; ++cg) {
                float4 bv4 = *(const float4*)&bl1[cg * 16 + lk * 4];
                f16x2 h01 = { (f16)(acc[pg][cg][0] + bv4.x), (f16)(acc[pg][cg][1] + bv4.y) };
                f16x2 h23 = { (f16)(acc[pg][cg][2] + bv4.z), (f16)(acc[pg][cg][3] + bv4.w) };
                uint2 st; st.x = hAsU(h01); st.y = hAsU(h23);
                *(uint2*)(slab + pos * 60 + cg * 16 + lk * 4) = st;
            }
        }
        __syncthreads();

        // depthwise: 768 units = 64 (d,h)-rows x 12 4-ch groups
        f16* outb = ((which == 0) ? qo : ko) + (size_t)b * 512 * 96;
        #pragma unroll
        for (int half = 0; half < 2; ++half) {
            if (half == 1 && tid >= 256) break;
            const int u = half * 512 + tid;
            const int r = u / 12;
            const int g4 = u - r * 12;
            const int dd = r >> 3, hh = r & 7;
            const int col = g4 * 4;
            float mo[8][4];
            {
                float4 b0 = *(const float4*)&bld[col];
                #pragma unroll
                for (int w = 0; w < 8; ++w) {
                    mo[w][0] = b0.x; mo[w][1] = b0.y; mo[w][2] = b0.z; mo[w][3] = b0.w;
                }
            }
            #pragma unroll
            for (int kd = 0; kd < 3; ++kd) {
                const int d2 = dd + kd - 1;
                const bool vd = (unsigned)d2 < 8u;
                f16x2 pa[8][2];
                #pragma unroll
                for (int w = 0; w < 8; ++w) {
                    pa[w][0] = f16x2{0, 0}; pa[w][1] = f16x2{0, 0};
                }
                #pragma unroll
                for (int kh = 0; kh < 3; ++kh) {
                    const int h2 = hh + kh - 1;
                    const unsigned vm = (vd && ((unsigned)h2 < 8u)) ? 0xFFFFFFFFu : 0u;
                    const int base = (vm ? (d2 * 64 + h2 * 8) : 0) * 60 + col;
                    U2H in[8];
                    #pragma unroll
                    for (int w2 = 0; w2 < 8; ++w2)
                        in[w2].q = *(const uint2*)(slab + base + w2 * 60);
                    const int t0 = (kd * 3 + kh) * 3;
                    f16x2 wt0[2], wt1[2], wt2[2];
                    #pragma unroll
                    for (int p = 0; p < 2; ++p) {
                        wt0[p] = uAsH(wdh[(t0 + 0) * 24 + g4 * 2 + p] & vm);
                        wt1[p] = uAsH(wdh[(t0 + 1) * 24 + g4 * 2 + p] & vm);
                        wt2[p] = uAsH(wdh[(t0 + 2) * 24 + g4 * 2 + p] & vm);
                    }
                    #pragma unroll
                    for (int w = 0; w < 8; ++w) {
                        #pragma unroll
                        for (int p = 0; p < 2; ++p) {
                            f16x2 s = pa[w][p];
                            s = in[w].h[p] * wt1[p] + s;
                            if (w > 0) s = in[w - 1].h[p] * wt0[p] + s;
                            if (w < 7) s = in[w + 1].h[p] * wt2[p] + s;
                            pa[w][p] = s;
                        }
                    }
                }
                #pragma unroll
                for (int w = 0; w < 8; ++w)
                    #pragma unroll
                    for (int p = 0; p < 2; ++p) {
                        mo[w][2 * p]     += (float)pa[w][p].x;
                        mo[w][2 * p + 1] += (float)pa[w][p].y;
                    }
            }
            #pragma unroll
            for (int w = 0; w < 8; ++w) {
                f16x2 h0 = { (f16)mo[w][0], (f16)mo[w][1] };
                f16x2 h1 = { (f16)mo[w][2], (f16)mo[w][3] };
                uint2 st; st.x = hAsU(h0); st.y = hAsU(h1);
                *(uint2*)(outb + (size_t)(r * 8 + w) * 96 + ch0 + col) = st;
            }
        }
    } else {
        f16*      Vsh = (f16*)sm;                  // [48][520] GEMM out
        f16*      Wsh = (f16*)(sm + 49920);        // [48][104]
        unsigned* wdp = (unsigned*)(sm + 59904);   // [48][27] {w,w} pairs
        float*    bl1 = (float*)(sm + 65088);      // [48]
        float*    bld = (float*)(sm + 65280);      // [48]

        #pragma unroll
        for (int it = 0; it < 3; ++it) {
            int g = tid + it * 512;
            if (g < 1152) {
                int i = g * 4;
                int co = i / 96, ci = i % 96;
                float4 v4 = *(const float4*)(w1 + (size_t)(ch0 + co) * 96 + ci);
                f16x2 h01 = { (f16)v4.x, (f16)v4.y };
                f16x2 h23 = { (f16)v4.z, (f16)v4.w };
                uint2 st; st.x = hAsU(h01); st.y = hAsU(h23);
                *(uint2*)(Wsh + co * 104 + ci) = st;
            }
        }
        for (int ii = tid; ii < 1296; ii += 512) {
            int lc = ii / 27, t2 = ii % 27;
            f16 hh = (f16)wd[(ch0 + lc) * 27 + t2];
            f16x2 hp = { hh, hh };
            wdp[lc * 27 + t2] = hAsU(hp);
        }
        if (tid < 48) { bl1[tid] = b1[ch0 + tid]; bld[tid] = bd[ch0 + tid]; }
        __syncthreads();

        // GEMM (unswapped: C quad = positions). A from global, W from LDS.
        f32x4 acc[4][3];
        #pragma unroll
        for (int pg = 0; pg < 4; ++pg)
            #pragma unroll
            for (int cg = 0; cg < 3; ++cg) acc[pg][cg] = f32x4{0.f, 0.f, 0.f, 0.f};
        #pragma unroll
        for (int ks = 0; ks < 3; ++ks) {
            f16x8 bfr[3];
            #pragma unroll
            for (int cg = 0; cg < 3; ++cg)
                bfr[cg] = *(const f16x8*)(Wsh + (cg * 16 + lr) * 104 + ks * 32 + lk * 8);
            #pragma unroll
            for (int pg = 0; pg < 4; ++pg) {
                f16x8 a = ld8cvt(xb + (size_t)(wv_ * 64 + pg * 16 + lr) * 96 + ks * 32 + lk * 8);
                #pragma unroll
                for (int cg = 0; cg < 3; ++cg)
                    acc[pg][cg] = __builtin_amdgcn_mfma_f32_16x16x32_f16(a, bfr[cg], acc[pg][cg], 0, 0, 0);
            }
        }
        __syncthreads();

        // writeback [ch][pos], stride 520; pos quad = lk*4+reg
        #pragma unroll
        for (int pg = 0; pg < 4; ++pg) {
            int pos = wv_ * 64 + pg * 16 + lk * 4;
            #pragma unroll
            for (int cg = 0; cg < 3; ++cg) {
                float bv = bl1[cg * 16 + lr];
                int lc = cg * 16 + lr;
                f16x2 h01 = { (f16)(acc[pg][cg][0] + bv), (f16)(acc[pg][cg][1] + bv) };
                f16x2 h23 = { (f16)(acc[pg][cg][2] + bv), (f16)(acc[pg][cg][3] + bv) };
                uint2 st; st.x = hAsU(h01); st.y = hAsU(h23);
                *(uint2*)(Vsh + lc * 520 + pos) = st;
            }
        }
        __syncthreads();

        // depthwise shift-register: 3072 units = 48 ch x 64 octets
        f16* outb = vo + (size_t)b * 96 * 512;
        #pragma unroll
        for (int j = 0; j < 6; ++j) {
            int u = tid + j * 512;
            int c = u >> 6, dh = u & 63;
            int dd = dh >> 3, hh2 = dh & 7;
            f16x2 A0[4], A1[4], A2[4];
            #pragma unroll
            for (int p = 0; p < 4; ++p) {
                A0[p] = f16x2{0, 0}; A1[p] = f16x2{0, 0}; A2[p] = f16x2{0, 0};
            }
            #pragma unroll
            for (int kd = 0; kd < 3; ++kd) {
                int d2 = dd + kd - 1;
                unsigned vd_ = ((unsigned)d2 < 8u) ? 0xFFFFFFFFu : 0u;
                #pragma unroll
                for (int kh = 0; kh < 3; ++kh) {
                    int h2 = hh2 + kh - 1;
                    unsigned vm = ((((unsigned)h2 < 8u) ? 0xFFFFFFFFu : 0u) & vd_);
                    int rowoff = vm ? ((d2 * 8 + h2) * 8) : 0;
                    uint4 rw = *(const uint4*)(Vsh + c * 520 + rowoff);
                    unsigned r0 = rw.x, r1 = rw.y, r2 = rw.z, r3 = rw.w;
                    unsigned ms0 = r0 << 16;
                    unsigned ms1 = (r1 << 16) | (r0 >> 16);
                    unsigned ms2 = (r2 << 16) | (r1 >> 16);
                    unsigned ms3 = (r3 << 16) | (r2 >> 16);
                    unsigned ms4 = r3 >> 16;
                    int t0 = kd * 9 + kh * 3;
                    f16x2 w0 = uAsH(wdp[c * 27 + t0]     & vm);
                    f16x2 w1 = uAsH(wdp[c * 27 + t0 + 1] & vm);
                    f16x2 w2 = uAsH(wdp[c * 27 + t0 + 2] & vm);
                    f16x2* acc2 = (kd == 0) ? A0 : ((kd == 1) ? A1 : A2);
                    acc2[0] = uAsH(ms0) * w0 + acc2[0];
                    acc2[1] = uAsH(ms1) * w0 + acc2[1];
                    acc2[2] = uAsH(ms2) * w0 + acc2[2];
                    acc2[3] = uAsH(ms3) * w0 + acc2[3];
                    acc2[0] = uAsH(r0) * w1 + acc2[0];
                    acc2[1] = uAsH(r1) * w1 + acc2[1];
                    acc2[2] = uAsH(r2) * w1 + acc2[2];
                    acc2[3] = uAsH(r3) * w1 + acc2[3];
                    acc2[0] = uAsH(ms1) * w2 + acc2[0];
                    acc2[1] = uAsH(ms2) * w2 + acc2[1];
                    acc2[2] = uAsH(ms3) * w2 + acc2[2];
                    acc2[3] = uAsH(ms4) * w2 + acc2[3];
                }
            }
            float bv = bld[c];
            unsigned ow[4];
            #pragma unroll
            for (int p = 0; p < 4; ++p) {
                float lo = (float)A0[p].x + (float)A1[p].x + (float)A2[p].x + bv;
                float hi = (float)A0[p].y + (float)A1[p].y + (float)A2[p].y + bv;
                f16x2 hp = { (f16)lo, (f16)hi };
                ow[p] = hAsU(hp);
            }
            *(uint4*)(outb + (size_t)(ch0 + c) * 512 + dh * 8) = make_uint4(ow[0], ow[1], ow[2], ow[3]);
        }
    }
}

// ---------------------------------------------------------------------------
// K3 v7 (unchanged): single-pass softmax, kf + vb hoisted per tile,
// qf streamed per q-group, 512 threads (8 waves x 64 q-rows). grid 512.
// ---------------------------------------------------------------------------
__global__ __launch_bounds__(512) void k3_attn(
    const f16* __restrict__ qF, const f16* __restrict__ kF, const f16* __restrict__ vF,
    float* __restrict__ outp)
{
    __shared__ __align__(16) f16 Ksh[512 * 104];   // 106496 B
    __shared__ __align__(16) f16 Psh[8 * 1152];    // 8 waves x [16 q][72 k]

    const int tid = threadIdx.x;
    const int b = blockIdx.x;
    const int wv_ = tid >> 6, lane = tid & 63, lr = lane & 15, lk = lane >> 4;

    const f16* qg = qF + ((size_t)b * 512 + wv_ * 64) * 96;
    const f16* kg = kF + (size_t)b * 512 * 96;
    const f16* vg = vF + (size_t)b * 96 * 512;

    const float scl = 0.14724447f;   // log2(e)/sqrt(96), applied post-MFMA

    #pragma unroll
    for (int it = 0; it < 12; ++it) {
        int i = tid * 8 + it * 4096;
        int r = i / 96, c = i % 96;
        *(uint4*)(Ksh + r * 104 + c) = *(const uint4*)(kg + i);
    }
    __syncthreads();

    float sum_p[4] = {0.f, 0.f, 0.f, 0.f};
    f32x4 accO[4][6];
    #pragma unroll
    for (int qg2 = 0; qg2 < 4; ++qg2)
        #pragma unroll
        for (int cg = 0; cg < 6; ++cg) accO[qg2][cg] = f32x4{0.f, 0.f, 0.f, 0.f};

    f16* psw = Psh + wv_ * 1152;
    uint2* psw2 = (uint2*)psw;

    for (int t = 0; t < 8; ++t) {
        f16x8 kf[3][4];
        #pragma unroll
        for (int ks3 = 0; ks3 < 3; ++ks3)
            #pragma unroll
            for (int f = 0; f < 4; ++f)
                kf[ks3][f] = *(const f16x8*)(Ksh + (t * 64 + f * 16 + lr) * 104 + ks3 * 32 + lk * 8);
        f16x8 vb[2][6];
        #pragma unroll
        for (int ks2 = 0; ks2 < 2; ++ks2)
            #pragma unroll
            for (int cg = 0; cg < 6; ++cg)
                vb[ks2][cg] = *(const f16x8*)(vg + (size_t)(cg * 16 + lr) * 512
                                                 + t * 64 + ks2 * 32 + lk * 8);
        #pragma unroll
        for (int qg2 = 0; qg2 < 4; ++qg2) {
            f16x8 qf3[3];
            #pragma unroll
            for (int ks3 = 0; ks3 < 3; ++ks3)
                qf3[ks3] = *(const f16x8*)(qg + (qg2 * 16 + lr) * 96 + ks3 * 32 + lk * 8);
            f32x4 sa[4];
            #pragma unroll
            for (int f = 0; f < 4; ++f) sa[f] = f32x4{0.f, 0.f, 0.f, 0.f};
            #pragma unroll
            for (int ks3 = 0; ks3 < 3; ++ks3)
                #pragma unroll
                for (int f = 0; f < 4; ++f)
                    sa[f] = __builtin_amdgcn_mfma_f32_16x16x32_f16(kf[ks3][f], qf3[ks3], sa[f], 0, 0, 0);
            #pragma unroll
            for (int f = 0; f < 4; ++f) {
                float e0 = __builtin_amdgcn_exp2f(sa[f][0] * scl);
                float e1 = __builtin_amdgcn_exp2f(sa[f][1] * scl);
                float e2 = __builtin_amdgcn_exp2f(sa[f][2] * scl);
                float e3 = __builtin_amdgcn_exp2f(sa[f][3] * scl);
                sum_p[qg2] += (e0 + e1) + (e2 + e3);
                uint2 pk;
                pk.x = pAsU(__builtin_amdgcn_cvt_pkrtz(e0, e1));
                pk.y = pAsU(__builtin_amdgcn_cvt_pkrtz(e2, e3));
                psw2[lr * 18 + f * 4 + lk] = pk;
            }
            #pragma unroll
            for (int ks2 = 0; ks2 < 2; ++ks2) {
                f16x8 pb = *(const f16x8*)(psw + lr * 72 + ks2 * 32 + lk * 8);
                #pragma unroll
                for (int cg = 0; cg < 6; ++cg)
                    accO[qg2][cg] = __builtin_amdgcn_mfma_f32_16x16x32_f16(
                        vb[ks2][cg], pb, accO[qg2][cg], 0, 0, 0);
            }
        }
    }
    #pragma unroll
    for (int qg2 = 0; qg2 < 4; ++qg2) {
        sum_p[qg2] += __shfl_xor(sum_p[qg2], 16);
        sum_p[qg2] += __shfl_xor(sum_p[qg2], 32);
    }

    #pragma unroll
    for (int qg2 = 0; qg2 < 4; ++qg2) {
        const float inv = 1.0f / sum_p[qg2];
        float* og = outp + ((size_t)b * 512 + wv_ * 64 + qg2 * 16 + lr) * 96;
        #pragma unroll
        for (int cg = 0; cg < 6; ++cg) {
            float4 o4 = make_float4(accO[qg2][cg][0] * inv, accO[qg2][cg][1] * inv,
                                    accO[qg2][cg][2] * inv, accO[qg2][cg][3] * inv);
            *(float4*)(og + cg * 16 + lk * 4) = o4;
        }
    }
}

extern "C" void kernel_launch(void* const* d_in, const int* in_sizes, int n_in,
                              void* d_out, int out_size, void* d_ws, size_t ws_size,
                              hipStream_t stream) {
    const float* x   = (const float*)d_in[0];
    const float* wq1 = (const float*)d_in[1];
    const float* bq1 = (const float*)d_in[2];
    const float* wk1 = (const float*)d_in[3];
    const float* bk1 = (const float*)d_in[4];
    const float* wv1 = (const float*)d_in[5];
    const float* bv1 = (const float*)d_in[6];
    const float* wqd = (const float*)d_in[7];
    const float* bqd = (const float*)d_in[8];
    const float* wkd = (const float*)d_in[9];
    const float* bkd = (const float*)d_in[10];
    const float* wvd = (const float*)d_in[11];
    const float* bvd = (const float*)d_in[12];

    f16* ws = (f16*)d_ws;
    f16* q = ws;
    f16* k = ws + PL;
    f16* v = ws + 2 * PL;

    k12_fused<<<3072, 512, 0, stream>>>(x, wq1, bq1, wk1, bk1, wv1, bv1,
                                        wqd, bqd, wkd, bkd, wvd, bvd, q, k, v);
    k3_attn<<<512, 512, 0, stream>>>(q, k, v, (float*)d_out);
}